// Round 8
// baseline (247.707 us; speedup 1.0000x reference)
//
#include <hip/hip_runtime.h>
#include <hip/hip_bf16.h>

// VolatilityModulatedAttention: B=2, S=4096, H=512, NH=8, HD=64
// Round 8: (a) V-frags read from global (Vsh deleted -> 34.8KB LDS, 4
// blocks/CU); (b) combine kernel eliminated: attn stores RAW fp16 O-partials
// (V prescaled by 1/4), proj fuses (O0+O1)*4/(l0+l1) into A-staging and runs
// f16 MFMA with preconverted fp16 W. 3 kernels.

#define S_LEN 4096
#define NHEAD 8
#define HD 64
#define HTOT 512

typedef __attribute__((ext_vector_type(8))) short short8;
typedef __attribute__((ext_vector_type(4))) float floatx4;
typedef __attribute__((ext_vector_type(8))) _Float16 half8;

#if __has_builtin(__builtin_amdgcn_exp2f)
#define EXP2F(x) __builtin_amdgcn_exp2f(x)
#else
#define EXP2F(x) exp2f(x)
#endif

__device__ __forceinline__ unsigned pack_bf16(float a, float b) {
    unsigned ua = __builtin_bit_cast(unsigned, a) + 0x8000u;
    unsigned ub = __builtin_bit_cast(unsigned, b) + 0x8000u;
    return __builtin_amdgcn_perm(ub, ua, 0x07060302u);
}

__device__ __forceinline__ unsigned short f2bf(float x) {
    unsigned u = __builtin_bit_cast(unsigned, x) + 0x8000u;
    return (unsigned short)(u >> 16);
}

__device__ __forceinline__ void async16(const unsigned short* g, unsigned short* l) {
    __builtin_amdgcn_global_load_lds(
        (const __attribute__((address_space(1))) unsigned int*)g,
        (__attribute__((address_space(3))) unsigned int*)l, 16, 0, 0);
}

// ---------------------------------------------------------------------------
// Prepass. [0,2048): K fp32->bf16. [2048,3072): V -> bf16*0.25 per-head
// transpose Vt[B*8][64][4096]. [3072,3200): W fp32->fp16.
// ---------------------------------------------------------------------------
__global__ __launch_bounds__(256) void prep_kernel(
    const float* __restrict__ K, unsigned short* __restrict__ K16,
    const float* __restrict__ V, unsigned short* __restrict__ Vt,
    const float* __restrict__ W, _Float16* __restrict__ W16h)
{
    const int tid = threadIdx.x;
    if (blockIdx.x >= 3072) {
        size_t i = ((size_t)(blockIdx.x - 3072) * 256 + tid) * 8;
        float4 a = *(const float4*)(W + i);
        float4 b = *(const float4*)(W + i + 4);
        half8 o = {(_Float16)a.x, (_Float16)a.y, (_Float16)a.z, (_Float16)a.w,
                   (_Float16)b.x, (_Float16)b.y, (_Float16)b.z, (_Float16)b.w};
        *(half8*)(W16h + i) = o;
    } else if (blockIdx.x < 2048) {
        size_t i = ((size_t)blockIdx.x * 256 + tid) * 8;
        float4 a = *(const float4*)(K + i);
        float4 b = *(const float4*)(K + i + 4);
        unsigned o[4] = {pack_bf16(a.x, a.y), pack_bf16(a.z, a.w),
                         pack_bf16(b.x, b.y), pack_bf16(b.z, b.w)};
        *(short8*)(K16 + i) = *(short8*)o;
    } else {
        __shared__ unsigned short T[64 * 66];   // [d][s]
        const int blk = blockIdx.x - 2048;
        const int st = blk & 63;
        const int bh = blk >> 6;
        const int b = bh >> 3, h = bh & 7;
        const float* src = V + ((size_t)b * S_LEN + st * 64) * HTOT + h * HD;
        for (int i = 0; i < 4; i++) {
            int idx = tid + i * 256;
            int s = idx >> 4, c4 = idx & 15;
            float4 v = *(const float4*)(src + (size_t)s * HTOT + c4 * 4);
            // scale by 1/4 (exact) for fp16 raw-O headroom downstream
            T[(c4 * 4 + 0) * 66 + s] = f2bf(v.x * 0.25f);
            T[(c4 * 4 + 1) * 66 + s] = f2bf(v.y * 0.25f);
            T[(c4 * 4 + 2) * 66 + s] = f2bf(v.z * 0.25f);
            T[(c4 * 4 + 3) * 66 + s] = f2bf(v.w * 0.25f);
        }
        __syncthreads();
        unsigned short* dst = Vt + ((size_t)bh * 64) * S_LEN + st * 64;
        for (int i = 0; i < 2; i++) {
            int idx = tid + i * 256;
            int d = idx >> 3, c8 = idx & 7;
            uint2 lo = *(const uint2*)&T[d * 66 + c8 * 8];
            uint2 hi = *(const uint2*)&T[d * 66 + c8 * 8 + 4];
            unsigned o[4] = {lo.x, lo.y, hi.x, hi.y};
            *(short8*)(dst + (size_t)d * S_LEN + c8 * 8) = *(short8*)o;
        }
    }
}

// ---------------------------------------------------------------------------
// Flash attention, K-split x2. Grid 1024, 4 blocks/CU (34.8 KB LDS).
// K staged via dbuf DMA; V-frags read directly from global Vt (L2-resident).
// Emits raw fp16 O-partials + l-sums (no normalization here).
// ---------------------------------------------------------------------------
__global__ __launch_bounds__(256, 4) void attn_kernel(
    const float* __restrict__ Q, const unsigned short* __restrict__ K16,
    const unsigned short* __restrict__ Vt,
    const float* __restrict__ risk_sigma, const float* __restrict__ risk_lambda,
    _Float16* __restrict__ Opart, float* __restrict__ Lpart)
{
    __shared__ unsigned short QPsh[128 * 72];   // Q tile, then per-wave P
    __shared__ unsigned short Ksh[2][64 * 64];  // [key][d] swizzled, dbuf

    const int tid  = threadIdx.x;
    const int wave = tid >> 6;
    const int lane = tid & 63;
    const int quad = lane >> 4;
    const int ln   = lane & 15;
    const int sw   = ln & 7;

    const int bid = blockIdx.x;                 // = ((b*8+h)*32+qt)*2+ks
    const int ks  = bid & 1;
    const int qt  = (bid >> 1) & 31;
    const int h   = (bid >> 6) & 7;
    const int b   = bid >> 9;
    const int qbase = qt * 128;

    float sig = risk_sigma[b];
    sig = fminf(fmaxf(sig, 0.001f), 0.2f);
    const float sn   = (sig - 0.001f) * (1.0f / 0.199f);
    const float coef = risk_lambda[0] * 0.1f * sn;
    const float nc2 = -coef * (1.0f / 4096.0f) * (1.0f / 4096.0f) * 1.4426950408889634f;
    const float qscale = 0.125f * 1.4426950408889634f;

    const float* Qb = Q + (size_t)b * S_LEN * HTOT + (size_t)h * HD;
    const unsigned short* Kb = K16 + (size_t)b * S_LEN * HTOT + (size_t)h * HD;
    const unsigned short* Vb = Vt + ((size_t)(b * 8 + h) * 64) * S_LEN;

    const int rl  = lane >> 3;
    const int c8g = ((lane & 7) ^ rl) << 3;
    auto dmaK = [&](int buf, int kbase) {
        const unsigned short* gk = Kb + (size_t)(kbase + wave * 8 + rl) * HTOT + c8g;
        async16(gk,             &Ksh[buf][wave * 512 + lane * 8]);
        async16(gk + 32 * HTOT, &Ksh[buf][(wave + 4) * 512 + lane * 8]);
    };

    dmaK(0, ks * 2048);
    for (int i = 0; i < 8; i++) {
        int idx = tid + i * 256;
        int r = idx >> 4, c4 = idx & 15;
        float4 v = *(const float4*)(Qb + (size_t)(qbase + r) * HTOT + c4 * 4);
        uint2 o;
        o.x = pack_bf16(v.x * qscale, v.y * qscale);
        o.y = pack_bf16(v.z * qscale, v.w * qscale);
        *(uint2*)&QPsh[r * 72 + c4 * 4] = o;
    }
    __syncthreads();

    short8 qf[2][2];
    for (int nt = 0; nt < 2; nt++) {
        qf[nt][0] = *(const short8*)&QPsh[(wave * 32 + nt * 16 + ln) * 72 + quad * 8];
        qf[nt][1] = *(const short8*)&QPsh[(wave * 32 + nt * 16 + ln) * 72 + 32 + quad * 8];
    }
    unsigned short* Pw = &QPsh[wave * 32 * 72];

    const short sone = (short)0x3F80;
    const short8 ones = {sone, sone, sone, sone, sone, sone, sone, sone};

    floatx4 Oacc[2][4], Lacc[2];
    for (int nt = 0; nt < 2; nt++) {
        Lacc[nt] = (floatx4){0.f, 0.f, 0.f, 0.f};
        for (int dt = 0; dt < 4; dt++) Oacc[nt][dt] = (floatx4){0.f, 0.f, 0.f, 0.f};
    }

    const int qa = qbase + wave * 32;
    const unsigned short* vrow = Vb + (size_t)ln * S_LEN + quad * 8;

    for (int kt = 0; kt < 32; ++kt) {
        const int kbase = ks * 2048 + kt * 64;
        const int cur = kt & 1;
        if (kt < 31) dmaK(1 - cur, kbase + 64);
        const unsigned short* Kc = Ksh[cur];

        // ---- S^T = K * Q^T, softmax, packed b64 P write ----
        const float dq = (float)(qa + ln - kbase);
        for (int jt = 0; jt < 4; jt++) {
            const int krow = (jt * 16 + ln) * 64;
            short8 ak0 = *(const short8*)&Kc[krow + ((quad ^ sw) << 3)];
            short8 ak1 = *(const short8*)&Kc[krow + (((quad + 4) ^ sw) << 3)];
            #pragma unroll
            for (int nt = 0; nt < 2; nt++) {
                floatx4 s = (floatx4){0.f, 0.f, 0.f, 0.f};
                s = __builtin_amdgcn_mfma_f32_16x16x32_bf16(ak0, qf[nt][0], s, 0, 0, 0);
                s = __builtin_amdgcn_mfma_f32_16x16x32_bf16(ak1, qf[nt][1], s, 0, 0, 0);
                float d = dq + (float)(nt * 16 - jt * 16 - quad * 4);
                float p[4];
                #pragma unroll
                for (int r = 0; r < 4; r++) {
                    float arg = __builtin_fmaf(nc2, d * d, s[r]);
                    p[r] = EXP2F(arg);
                    d -= 1.0f;
                }
                uint2 o;
                o.x = pack_bf16(p[0], p[1]);
                o.y = pack_bf16(p[2], p[3]);
                *(uint2*)&Pw[(nt * 16 + ln) * 72 + jt * 16 + quad * 4] = o;
            }
        }
        asm volatile("s_waitcnt lgkmcnt(0)" ::: "memory");
        __builtin_amdgcn_wave_barrier();

        // ---- PV: V-frags direct from global (L2-resident Vt) ----
        short8 bv[4][2];
        #pragma unroll
        for (int dt = 0; dt < 4; dt++) {
            const unsigned short* vp = vrow + (size_t)dt * 16 * S_LEN + kbase;
            bv[dt][0] = *(const short8*)vp;
            bv[dt][1] = *(const short8*)(vp + 32);
        }
        short8 pf[2][2];
        for (int nt = 0; nt < 2; nt++) {
            pf[nt][0] = *(const short8*)&Pw[(nt * 16 + ln) * 72 + quad * 8];
            pf[nt][1] = *(const short8*)&Pw[(nt * 16 + ln) * 72 + 32 + quad * 8];
        }
        for (int dt = 0; dt < 4; dt++) {
            #pragma unroll
            for (int nt = 0; nt < 2; nt++) {
                Oacc[nt][dt] = __builtin_amdgcn_mfma_f32_16x16x32_bf16(pf[nt][0], bv[dt][0], Oacc[nt][dt], 0, 0, 0);
                Oacc[nt][dt] = __builtin_amdgcn_mfma_f32_16x16x32_bf16(pf[nt][1], bv[dt][1], Oacc[nt][dt], 0, 0, 0);
            }
        }
        #pragma unroll
        for (int nt = 0; nt < 2; nt++) {
            Lacc[nt] = __builtin_amdgcn_mfma_f32_16x16x32_bf16(pf[nt][0], ones, Lacc[nt], 0, 0, 0);
            Lacc[nt] = __builtin_amdgcn_mfma_f32_16x16x32_bf16(pf[nt][1], ones, Lacc[nt], 0, 0, 0);
        }
        __syncthreads();   // cur reads done; prefetch DMA drained
    }

    // ---- epilogue: raw fp16 O-partial + l (no normalization) ----
    _Float16* Ow = Opart + (size_t)ks * (S_LEN * 2 * HTOT);
    float* Lw = Lpart + ks * 65536 + ((b * 8 + h) << 12);
    for (int nt = 0; nt < 2; nt++) {
        if (ln == 0) {
            #pragma unroll
            for (int r = 0; r < 4; r++)
                Lw[qa + nt * 16 + quad * 4 + r] = Lacc[nt][r];
        }
        for (int dt = 0; dt < 4; dt++)
            #pragma unroll
            for (int r = 0; r < 4; r++) {
                int q = qa + nt * 16 + quad * 4 + r;
                Ow[((size_t)b * S_LEN + q) * HTOT + h * HD + dt * 16 + ln] =
                    (_Float16)Oacc[nt][dt][r];
            }
    }
}

// ---------------------------------------------------------------------------
// Projection GEMM with fused K-split sum + normalization, all-fp16 MFMA.
// out[m][n] = sum_k [(O0+O1)[m][k] * 4/(l0+l1)[m][k>>6]] * W[n][k] + bias[n]
// 64x128 tiles, grid (4,128). W via DMA dbuf; A staged with pk_add/pk_mul.
// ---------------------------------------------------------------------------
__global__ __launch_bounds__(256) void proj_kernel(
    const _Float16* __restrict__ Opart, const float* __restrict__ Lpart,
    const _Float16* __restrict__ W16h, const float* __restrict__ bias,
    float* __restrict__ out)
{
    __shared__ unsigned short Ash[2][64 * 32];
    __shared__ unsigned short Bsh[2][128 * 32];
    __shared__ float Lw[8][64];

    const int tid = threadIdx.x;
    const int wave = tid >> 6, lane = tid & 63, quad = lane >> 4, ln = lane & 15;
    const int wr = wave >> 1, wc = wave & 1;
    const int m0 = blockIdx.y * 64;
    const int nb = blockIdx.x * 128;

    // per-row per-head normalization weights: 4/(l0+l1)
    for (int i = 0; i < 2; i++) {
        int e = tid + i * 256;                 // 512 (h,row) pairs
        int hh = e >> 6, r = e & 63;
        int m = m0 + r, bb = m >> 12, q = m & 4095;
        float l0 = Lpart[((bb * 8 + hh) << 12) + q];
        float l1 = Lpart[65536 + ((bb * 8 + hh) << 12) + q];
        Lw[hh][r] = 4.0f / (l0 + l1);
    }

    const _Float16* Op0 = Opart;
    const _Float16* Op1 = Opart + (size_t)S_LEN * 2 * HTOT;

    // W DMA lane geometry (R7 pattern)
    const int wrow0 = (wave * 64 + lane) >> 2;
    const int wc0   = (wave * 64 + lane) & 3;
    const int wcs0  = (wc0 ^ ((wrow0 >> 1) & 3)) << 3;
    const int wrow1 = wrow0 + 64;
    const int wcs1  = (wc0 ^ ((wrow1 >> 1) & 3)) << 3;
    auto dmaW = [&](int buf, int k0) {
        async16((const unsigned short*)W16h + (size_t)(nb + wrow0) * 512 + k0 + wcs0,
                &Bsh[buf][wave * 512 + lane * 8]);
        async16((const unsigned short*)W16h + (size_t)(nb + wrow1) * 512 + k0 + wcs1,
                &Bsh[buf][(wave + 4) * 512 + lane * 8]);
    };

    const int ar  = tid >> 2, ac8 = tid & 3;
    const int asw = (ac8 ^ ((ar >> 1) & 3)) << 3;
    auto stageA = [&](int buf, int k0) {
        const int hh = k0 >> 6;
        size_t off = (size_t)(m0 + ar) * 512 + k0 + ac8 * 8;
        half8 o0 = *(const half8*)(Op0 + off);
        half8 o1 = *(const half8*)(Op1 + off);
        _Float16 lh = (_Float16)Lw[hh][ar];
        half8 s = (o0 + o1) * lh;
        *(half8*)&Ash[buf][ar * 32 + asw] = s;
    };

    floatx4 acc[2][4];
    for (int i = 0; i < 2; i++)
        for (int j = 0; j < 4; j++) acc[i][j] = (floatx4){0.f, 0.f, 0.f, 0.f};

    __syncthreads();            // Lw visible
    dmaW(0, 0);
    stageA(0, 0);

    for (int kt = 0; kt < 16; ++kt) {
        const int cur = kt & 1;
        __syncthreads();        // cur ready; (1-cur) reads from kt-1 done
        if (kt < 15) { dmaW(1 - cur, (kt + 1) * 32); stageA(1 - cur, (kt + 1) * 32); }

        half8 af[2], bf[4];
        for (int i = 0; i < 2; i++) {
            int r = wr * 32 + i * 16 + ln;
            af[i] = __builtin_bit_cast(half8,
                *(const short8*)&Ash[cur][r * 32 + ((quad ^ ((r >> 1) & 3)) << 3)]);
        }
        for (int j = 0; j < 4; j++) {
            int r = wc * 64 + j * 16 + ln;
            bf[j] = __builtin_bit_cast(half8,
                *(const short8*)&Bsh[cur][r * 32 + ((quad ^ ((r >> 1) & 3)) << 3)]);
        }
        for (int i = 0; i < 2; i++)
            for (int j = 0; j < 4; j++)
                acc[i][j] = __builtin_amdgcn_mfma_f32_16x16x32_f16(af[i], bf[j], acc[i][j], 0, 0, 0);
    }

    for (int i = 0; i < 2; i++) {
        int row = m0 + wr * 32 + i * 16 + quad * 4;
        for (int j = 0; j < 4; j++) {
            int col = nb + wc * 64 + j * 16 + ln;
            float bv = bias[col];
            #pragma unroll
            for (int r = 0; r < 4; r++)
                out[(size_t)(row + r) * 512 + col] = acc[i][j][r] + bv;
        }
    }
}

extern "C" void kernel_launch(void* const* d_in, const int* in_sizes, int n_in,
                              void* d_out, int out_size, void* d_ws, size_t ws_size,
                              hipStream_t stream) {
    const float* Q    = (const float*)d_in[0];
    const float* K    = (const float*)d_in[1];
    const float* V    = (const float*)d_in[2];
    const float* sig  = (const float*)d_in[3];
    const float* lam  = (const float*)d_in[4];
    const float* W    = (const float*)d_in[5];
    const float* bias = (const float*)d_in[6];

    unsigned short* K16 = (unsigned short*)d_ws;                          // 8 MiB
    unsigned short* Vt  = (unsigned short*)((char*)d_ws + (8u << 20));    // 8 MiB
    _Float16* Opart     = (_Float16*)((char*)d_ws + (16u << 20));         // 16 MiB (2 x 8)
    float* Lpart        = (float*)((char*)d_ws + (32u << 20));            // 512 KiB
    _Float16* W16h      = (_Float16*)((char*)d_ws + (32u << 20) + (512u << 10)); // 512 KiB
    float* out = (float*)d_out;

    prep_kernel<<<dim3(3200), dim3(256), 0, stream>>>(K, K16, V, Vt, W, W16h);
    attn_kernel<<<dim3(1024), dim3(256), 0, stream>>>(Q, K16, Vt, sig, lam, Opart, Lpart);
    proj_kernel<<<dim3(4, 128), dim3(256), 0, stream>>>(Opart, Lpart, W16h, bias, out);
}